// Round 3
// baseline (60.216 us; speedup 1.0000x reference)
//
#include <hip/hip_runtime.h>

#define V   1024
#define NH  16384
#define NM  16384

#define BAND_LOW_MAX    500.0f
#define BAND_MID_MAX    2000.0f
#define ENERGY_THRESHOLD 0.5f

// clang native vector type: __builtin_nontemporal_* requires this (HIP's
// float4 is a class and is rejected by the builtin).
typedef float f32x4 __attribute__((ext_vector_type(4)));

// ---------------------------------------------------------------------------
// Pass 1: per-voice raw band energies (no actf factor). One block per voice.
// Regular (caching) loads: harm must stay L3-resident for pass 3's re-read.
// ---------------------------------------------------------------------------
__global__ __launch_bounds__(256)
void pass1_band_energy(const float* __restrict__ harm,
                       const float* __restrict__ f0_hz,
                       float* __restrict__ Eraw /* [V][3] */) {
    const int v = blockIdx.x;
    const float f0 = f0_hz[v];
    const f32x4* h4 = (const f32x4*)(harm + (size_t)v * NH);

    float e0 = 0.f, e1 = 0.f, e2 = 0.f;
    for (int c = threadIdx.x; c < NH / 4; c += 256) {
        f32x4 a = h4[c];
        const int hbase = c * 4;
        #pragma unroll
        for (int j = 0; j < 4; ++j) {
            float amp  = a[j];
            float freq = f0 * (float)(hbase + j + 1);   // matches jnp fp32 mul
            if (freq < BAND_LOW_MAX)       e0 += amp;
            else if (freq < BAND_MID_MAX)  e1 += amp;
            else                           e2 += amp;
        }
    }
    for (int off = 32; off > 0; off >>= 1) {
        e0 += __shfl_down(e0, off);
        e1 += __shfl_down(e1, off);
        e2 += __shfl_down(e2, off);
    }
    __shared__ float s[3][4];
    const int wid  = threadIdx.x >> 6;
    const int lane = threadIdx.x & 63;
    if (lane == 0) { s[0][wid] = e0; s[1][wid] = e1; s[2][wid] = e2; }
    __syncthreads();
    if (threadIdx.x == 0) {
        float t0 = 0.f, t1 = 0.f, t2 = 0.f;
        #pragma unroll
        for (int i = 0; i < 4; ++i) { t0 += s[0][i]; t1 += s[1][i]; t2 += s[2][i]; }
        Eraw[v * 3 + 0] = t0;
        Eraw[v * 3 + 1] = t1;
        Eraw[v * 3 + 2] = t2;
    }
}

// ---------------------------------------------------------------------------
// Pass 2: global reductions + per-voice gains. Single block, 1024 threads.
// ---------------------------------------------------------------------------
__global__ __launch_bounds__(1024)
void pass2_gains(const float* __restrict__ Eraw,
                 const float* __restrict__ cw,
                 const float* __restrict__ wd,       /* [V][3] */
                 const int*   __restrict__ is_active,
                 float* __restrict__ gains /* [V][4] */) {
    const int v = threadIdx.x;
    const float e0 = Eraw[v * 3 + 0];
    const float e1 = Eraw[v * 3 + 1];
    const float e2 = Eraw[v * 3 + 2];
    const bool  act  = (is_active[v] != 0);
    const float actf = act ? 1.0f : 0.0f;
    const float w    = cw[v];

    const float ea0 = e0 * actf, ea1 = e1 * actf, ea2 = e2 * actf;

    float r0 = ea0, r1 = ea1, r2 = ea2, r3 = w * actf, r4 = actf;
    for (int off = 32; off > 0; off >>= 1) {
        r0 += __shfl_down(r0, off);
        r1 += __shfl_down(r1, off);
        r2 += __shfl_down(r2, off);
        r3 += __shfl_down(r3, off);
        r4 += __shfl_down(r4, off);
    }
    __shared__ float s[5][16];
    __shared__ float tot[5];
    const int wid  = threadIdx.x >> 6;
    const int lane = threadIdx.x & 63;
    if (lane == 0) {
        s[0][wid] = r0; s[1][wid] = r1; s[2][wid] = r2;
        s[3][wid] = r3; s[4][wid] = r4;
    }
    __syncthreads();
    if (threadIdx.x < 5) {
        float t = 0.f;
        #pragma unroll
        for (int i = 0; i < 16; ++i) t += s[threadIdx.x][i];
        tot[threadIdx.x] = t;
    }
    __syncthreads();

    const float TE[3] = { tot[0], tot[1], tot[2] };
    const float TW    = tot[3];
    const bool changed = (tot[4] >= 1.5f);   // n_active >= 2

    const float claim = w / fmaxf(TW, 1e-6f);
    const float share = claim * ENERGY_THRESHOLD;

    const float ea[3] = { ea0, ea1, ea2 };
    const float er[3] = { e0, e1, e2 };

    const float tbefore = e0 + e1 + e2;
    float tafter = 0.f;
    float g[3];
    #pragma unroll
    for (int b = 0; b < 3; ++b) {
        const float excess = ea[b] - share;
        const float exr    = excess / fmaxf(ea[b], 1e-6f);
        const float red    = fmaxf(0.3f, 1.0f - wd[v * 3 + b] * exr * 0.5f);
        const bool apply   = (TE[b] > ENERGY_THRESHOLD) && (ea[b] > 0.0f) &&
                             (excess > 0.0f) && act;
        const float gb = apply ? red : 1.0f;
        tafter += gb * er[b];
        g[b] = changed ? gb : 1.0f;
    }

    const float nscale = (tbefore > 1e-6f) ? (tafter / tbefore) : 1.0f;
    const float nse = (changed && act) ? nscale : 1.0f;

    gains[v * 4 + 0] = g[0];
    gains[v * 4 + 1] = g[1];
    gains[v * 4 + 2] = g[2];
    gains[v * 4 + 3] = nse;
}

// ---------------------------------------------------------------------------
// Pass 3: elementwise apply. Each block = 512 float4 of one row (2/thread).
// 16 blocks per row; segments of 512 never straddle the harm/noise boundary
// (4096 % 512 == 0). v derived from blockIdx only -> scalar f0/gain loads.
// Noise loads + all out stores are NONTEMPORAL so harm stays L3-resident.
// ---------------------------------------------------------------------------
__global__ __launch_bounds__(256)
void pass3_apply(const float* __restrict__ harm,
                 const float* __restrict__ noise,
                 const float* __restrict__ f0_hz,
                 const float* __restrict__ gains,
                 float* __restrict__ out) {
    const int v   = blockIdx.x >> 4;           // 16 blocks per output row
    const int seg = (blockIdx.x & 15) << 9;    // 512-float4-aligned offset
    const int c0  = seg + threadIdx.x;

    f32x4* outrow = (f32x4*)out + (size_t)v * 8192;

    if (seg < 4096) {
        const float f0 = f0_hz[v];
        const float g0 = gains[v * 4 + 0];
        const float g1 = gains[v * 4 + 1];
        const float g2 = gains[v * 4 + 2];
        const f32x4* hrow = (const f32x4*)harm + (size_t)v * 4096;
        // two independent float4s for MLP
        const f32x4 a0 = hrow[c0];
        const f32x4 a1 = hrow[c0 + 256];
        f32x4 o0, o1;
        #pragma unroll
        for (int j = 0; j < 4; ++j) {
            const float fr0 = f0 * (float)(c0 * 4 + j + 1);
            const float fr1 = f0 * (float)((c0 + 256) * 4 + j + 1);
            const float ga = (fr0 < BAND_LOW_MAX) ? g0 : (fr0 < BAND_MID_MAX) ? g1 : g2;
            const float gb = (fr1 < BAND_LOW_MAX) ? g0 : (fr1 < BAND_MID_MAX) ? g1 : g2;
            o0[j] = a0[j] * ga;
            o1[j] = a1[j] * gb;
        }
        __builtin_nontemporal_store(o0, outrow + c0);
        __builtin_nontemporal_store(o1, outrow + c0 + 256);
    } else {
        const float ns = gains[v * 4 + 3];
        const f32x4* nrow = (const f32x4*)noise + (size_t)v * 4096 - 4096;  // +c indexes with c>=4096
        const f32x4 n0 = __builtin_nontemporal_load(nrow + c0);
        const f32x4 n1 = __builtin_nontemporal_load(nrow + c0 + 256);
        f32x4 o0, o1;
        o0 = n0 * ns;
        o1 = n1 * ns;
        __builtin_nontemporal_store(o0, outrow + c0);
        __builtin_nontemporal_store(o1, outrow + c0 + 256);
    }
}

// ---------------------------------------------------------------------------
extern "C" void kernel_launch(void* const* d_in, const int* in_sizes, int n_in,
                              void* d_out, int out_size, void* d_ws, size_t ws_size,
                              hipStream_t stream) {
    const float* harm  = (const float*)d_in[0];
    const float* noise = (const float*)d_in[1];
    const float* f0    = (const float*)d_in[2];
    const float* cw    = (const float*)d_in[3];
    const float* wd    = (const float*)d_in[4];
    const int*   act   = (const int*)d_in[5];
    float* out = (float*)d_out;

    float* Eraw  = (float*)d_ws;               // V*3 floats
    float* gains = Eraw + 4096;                // V*4 floats (offset 16 KiB)

    pass1_band_energy<<<V, 256, 0, stream>>>(harm, f0, Eraw);
    pass2_gains<<<1, 1024, 0, stream>>>(Eraw, cw, wd, act, gains);
    // V rows * 16 blocks/row, each block covers 512 float4 (2 per thread)
    pass3_apply<<<V * 16, 256, 0, stream>>>(harm, noise, f0, gains, out);
}